// Round 12
// baseline (368.343 us; speedup 1.0000x reference)
//
#include <hip/hip_runtime.h>
#include <hip/hip_bf16.h>

// Problem constants (fixed by setup_inputs)
#define M_ROWS 262144   // B*A*T = 16*64*256
#define TILE_M 64
#define BK 32
#define REP 64          // second-level stats partials (matches finalize_k layout)

typedef unsigned short ushort_t;
typedef unsigned int uint_t;
typedef __attribute__((ext_vector_type(8))) short short8_t;   // 8 bf16 = 4 VGPRs
typedef __attribute__((ext_vector_type(4))) float float4_t;   // MFMA acc

// bf16 (stored as ushort) <-> fp32 helpers. Load is exact; store is RNE.
__device__ __forceinline__ float b2f(ushort_t u) {
    union { uint_t i; float f; } c; c.i = ((uint_t)u) << 16; return c.f;
}
__device__ __forceinline__ ushort_t f2b(float f) {
    union { float f; uint_t i; } c; c.f = f;
    uint_t u = c.i;
    return (ushort_t)((u + 0x7fffu + ((u >> 16) & 1u)) >> 16);
}
// packed 2xfp32 -> 2xbf16 (v_cvt_pk_bf16_f32 on gfx950, RNE)
__device__ __forceinline__ uint_t pack2(float a, float b) {
    union { __hip_bfloat162 h; uint_t u; } c;
    c.h = __float22bfloat162_rn(make_float2(a, b));
    return c.u;
}

// async global->LDS DMA, 16 B per lane; data lands at ldsbase + lane*16
__device__ __forceinline__ void gld_lds16(const ushort_t* g, ushort_t* l) {
    __builtin_amdgcn_global_load_lds((const __attribute__((address_space(1))) void*)g,
                                     (__attribute__((address_space(3))) void*)l, 16, 0, 0);
}

// ---------------------------------------------------------------------------
// Layer-1 N-SPLIT pipelined GEMM (pure concat, NO act — X pre-materialized):
// C = [X, P] @ W1 + b1 (K=256). Grid 1024: tile = blockIdx&511, half =
// blockIdx>>9 -> all half-0 blocks (one full co-resident round of 512) stream
// X+P first; half-1's re-reads then hit the 256 MB L3. Sibling XCD mapping
// stays aligned (512 % 8 == 0). B half (64x256, 32 KB) resident; A double-
// buffered over (tile,kt) steps with one-step-ahead DMA prefetch. ~66 KB LDS
// -> 2 blocks/CU. C must not alias X/P (siblings read full rows) -> d_out.
// ---------------------------------------------------------------------------
template<int RPT>
__launch_bounds__(256)
__global__ void gemm1s_k(const ushort_t* __restrict__ X, const ushort_t* __restrict__ P,
                         const ushort_t* __restrict__ WT, const float* __restrict__ bias,
                         ushort_t* __restrict__ C, float* __restrict__ sumP, float* __restrict__ sqP) {
    __shared__ __attribute__((aligned(16))) ushort_t Bs[64 * 256];       // 32 KB
    __shared__ __attribute__((aligned(16))) ushort_t Abuf[2][64 * 128];  // 2x16 KB
    __shared__ float sred[4 * 64 * 2];

    const int tid = threadIdx.x;
    const int lane = tid & 63;
    const int wave = tid >> 6;
    const int wm = wave & 1, wn = wave >> 1;
    const int quad = lane >> 4, l16 = lane & 15;
    const int srow = lane >> 4, sp16 = lane & 15;   // A staging
    const int brow = lane >> 5, bs32 = lane & 31;   // B staging (512 B rows)
    const int tileId = blockIdx.x & 511;            // 512 tiles
    const int n0 = (blockIdx.x >> 9) * 64;          // column-half offset
    const int row0 = tileId * (RPT * 64);

    // ---- stage B half (rows n0..n0+63 of WT, 512 B each): 32 chunks x 1 KB ----
    #pragma unroll
    for (int i = 0; i < 8; ++i) {
        int t = i * 4 + wave;
        int r = t * 2 + brow;                        // local B row 0..63
        int sp = (bs32 & 16) | ((bs32 ^ r) & 15);    // half-preserving XOR swizzle
        gld_lds16(WT + (size_t)(n0 + r) * 256 + sp * 8, Bs + t * 512);
    }

    auto stageA = [&](int it, int kt, int buf) {
        const ushort_t* src = kt ? P : X;
        int r0 = row0 + it * 64;
        #pragma unroll
        for (int i = 0; i < 4; ++i) {
            int t = i * 4 + wave;
            int r = t * 4 + srow;
            int sp = sp16 ^ (r & 15);
            gld_lds16(src + (size_t)(r0 + r) * 128 + sp * 8, Abuf[buf] + t * 512);
        }
    };
    stageA(0, 0, 0);

    float bvs[2];
    #pragma unroll
    for (int nt = 0; nt < 2; ++nt) bvs[nt] = bias[n0 + wn * 32 + nt * 16 + l16];
    float sSum[2] = {0.f, 0.f}, sSq[2] = {0.f, 0.f};

    int step = 0;
    for (int it = 0; it < RPT; ++it) {
        float4_t acc[2][2];
        #pragma unroll
        for (int mt = 0; mt < 2; ++mt)
            #pragma unroll
            for (int nt = 0; nt < 2; ++nt) acc[mt][nt] = (float4_t)0.f;

        #pragma unroll
        for (int kt = 0; kt < 2; ++kt) {
            __syncthreads();   // A(step) [+Bs on step 0] resident; prior epi reads done
            if (step + 1 < 2 * RPT) {
                int ns = step + 1;
                stageA(ns >> 1, ns & 1, ns & 1);
            }
            const ushort_t* As = Abuf[step & 1];
            #pragma unroll
            for (int kk = 0; kk < 4; ++kk) {
                int j = kk * 4 + quad;
                short8_t a0 = *(const short8_t*)&As[(wm * 32 + l16) * 128 + ((j ^ l16) * 8)];
                short8_t a1 = *(const short8_t*)&As[(wm * 32 + 16 + l16) * 128 + ((j ^ l16) * 8)];
                #pragma unroll
                for (int nt = 0; nt < 2; ++nt) {
                    int br = wn * 32 + nt * 16 + l16;
                    short8_t bf = *(const short8_t*)&Bs[br * 256 + kt * 128 + ((j ^ l16) * 8)];
                    acc[0][nt] = __builtin_amdgcn_mfma_f32_16x16x32_bf16(a0, bf, acc[0][nt], 0, 0, 0);
                    acc[1][nt] = __builtin_amdgcn_mfma_f32_16x16x32_bf16(a1, bf, acc[1][nt], 0, 0, 0);
                }
            }
            ++step;
        }

        // ---- bias + stats accumulate ----
        #pragma unroll
        for (int mt = 0; mt < 2; ++mt)
            #pragma unroll
            for (int nt = 0; nt < 2; ++nt)
                #pragma unroll
                for (int r = 0; r < 4; ++r) {
                    float v = acc[mt][nt][r] + bvs[nt];
                    acc[mt][nt][r] = v;
                    sSum[nt] += v; sSq[nt] = fmaf(v, v, sSq[nt]);
                }
        if (it == RPT - 1) {
            #pragma unroll
            for (int nt = 0; nt < 2; ++nt) {
                float s = sSum[nt], q = sSq[nt];
                s += __shfl_xor(s, 16); q += __shfl_xor(q, 16);
                s += __shfl_xor(s, 32); q += __shfl_xor(q, 32);
                if (lane < 16) {
                    int colL = wn * 32 + nt * 16 + l16;
                    sred[(wave * 64 + colL) * 2 + 0] = s;
                    sred[(wave * 64 + colL) * 2 + 1] = q;
                }
            }
        }
        __syncthreads();   // kt=1 reads of Abuf[1] done; sred visible

        // ---- swizzled transpose into Abuf[1] (free; in-flight DMA targets buf0) ----
        char* eb = (char*)Abuf[1];
        #pragma unroll
        for (int mt = 0; mt < 2; ++mt)
            #pragma unroll
            for (int nt = 0; nt < 2; ++nt) {
                int colL = wn * 32 + nt * 16 + l16;
                int bc = colL * 2;
                #pragma unroll
                for (int r = 0; r < 4; ++r) {
                    int row = wm * 32 + mt * 16 + quad * 4 + r;
                    int addr = row * 128 + ((((bc >> 4) ^ (row & 7)) << 4) | (bc & 15));
                    *(ushort_t*)(eb + addr) = f2b(acc[mt][nt][r]);
                }
            }
        if (it == RPT - 1 && tid < 128) {
            int colL = tid & 63, qs = tid >> 6;
            int wb = (colL >> 5) * 2;   // the two waves (wm=0,1) owning this col
            float v = sred[(wb * 64 + colL) * 2 + qs] + sred[((wb + 1) * 64 + colL) * 2 + qs];
            (qs ? sqP : sumP)[(size_t)tileId * 128 + n0 + colL] = v;
        }
        __syncthreads();

        // ---- coalesced 16 B stores of the 64-col half (128 B per row) ----
        int r0s = row0 + it * 64;
        #pragma unroll
        for (int p = 0; p < 2; ++p) {
            int s = p * 256 + tid;
            int row = s >> 3, g = s & 7;
            uint4 v = *(const uint4*)(eb + row * 128 + ((g ^ (row & 7)) << 4));
            *(uint4*)((char*)(C + (size_t)(r0s + row) * 128 + n0) + g * 16) = v;
        }
    }
}

// ---------------------------------------------------------------------------
// Persistent pipelined MFMA GEMM for K=128 layers: C = act(A)@W + bias.
// ---------------------------------------------------------------------------
template<int N, int MODE, int STATS, int RPT, typename CT>
__launch_bounds__(256)
__global__ void mfma_gemm3_k(const ushort_t* __restrict__ A, const ushort_t* __restrict__ WT,
                             const float* __restrict__ bias,
                             const float* __restrict__ scale, const float* __restrict__ shift,
                             CT* __restrict__ C, float* __restrict__ sumP, float* __restrict__ sqP) {
    constexpr int WN = N / 2;        // cols per wave-column (64 or 32)
    constexpr int NT = WN / 16;      // 4 (N=128) or 2 (N=64)

    __shared__ __attribute__((aligned(16))) ushort_t Bs[N * 128];
    __shared__ __attribute__((aligned(16))) ushort_t Abuf[2][64 * 128];
    __shared__ float sred[STATS ? 4 * N * 2 : 1];
    __shared__ float s_sc[MODE == 1 ? 128 : 1];
    __shared__ float s_sh[MODE == 1 ? 128 : 1];

    const int tid = threadIdx.x;
    const int lane = tid & 63;
    const int wave = tid >> 6;
    const int wm = wave & 1;
    const int wn = wave >> 1;
    const int quad = lane >> 4;
    const int l16 = lane & 15;
    const int srow = lane >> 4;
    const int sp16 = lane & 15;

    if (MODE == 1 && tid < 128) { s_sc[tid] = scale[tid]; s_sh[tid] = shift[tid]; }

    #pragma unroll
    for (int i = 0; i < N / 16; ++i) {
        int t = i * 4 + wave;
        int r = t * 4 + srow;
        int sp = sp16 ^ (r & 15);
        gld_lds16(WT + (size_t)r * 128 + sp * 8, Bs + t * 512);
    }
    {
        int r0 = blockIdx.x * (RPT * 64);
        #pragma unroll
        for (int i = 0; i < 4; ++i) {
            int t = i * 4 + wave;
            int r = t * 4 + srow;
            int sp = sp16 ^ (r & 15);
            gld_lds16(A + (size_t)(r0 + r) * 128 + sp * 8, Abuf[0] + t * 512);
        }
    }

    float bvs[NT];
    #pragma unroll
    for (int nt = 0; nt < NT; ++nt) bvs[nt] = bias[wn * WN + nt * 16 + l16];
    float sSum[STATS ? NT : 1] = {0.f}, sSq[STATS ? NT : 1] = {0.f};

    for (int it = 0; it < RPT; ++it) {
        __syncthreads();
        if (it + 1 < RPT) {
            int r0 = blockIdx.x * (RPT * 64) + (it + 1) * 64;
            #pragma unroll
            for (int i = 0; i < 4; ++i) {
                int t = i * 4 + wave;
                int r = t * 4 + srow;
                int sp = sp16 ^ (r & 15);
                gld_lds16(A + (size_t)(r0 + r) * 128 + sp * 8, Abuf[(it + 1) & 1] + t * 512);
            }
        }
        const ushort_t* As = Abuf[it & 1];

        float4_t acc[2][NT];
        #pragma unroll
        for (int mt = 0; mt < 2; ++mt)
            #pragma unroll
            for (int nt = 0; nt < NT; ++nt) acc[mt][nt] = (float4_t)0.f;

        #pragma unroll
        for (int kk = 0; kk < 4; ++kk) {
            int j = kk * 4 + quad;
            short8_t a0 = *(const short8_t*)&As[(wm * 32 + l16) * 128 + ((j ^ l16) * 8)];
            short8_t a1 = *(const short8_t*)&As[(wm * 32 + 16 + l16) * 128 + ((j ^ l16) * 8)];
            if (MODE == 1) {
                int kb = kk * 32 + quad * 8;
                float4 c0 = *(const float4*)&s_sc[kb], c1 = *(const float4*)&s_sc[kb + 4];
                float4 h0 = *(const float4*)&s_sh[kb], h1 = *(const float4*)&s_sh[kb + 4];
                #pragma unroll
                for (int z = 0; z < 2; ++z) {
                    ushort_t u[8];
                    *(short8_t*)u = z ? a1 : a0;
                    uint_t w[4];
                    w[0] = pack2(fmaxf(fmaf(b2f(u[0]), c0.x, h0.x), 0.f),
                                 fmaxf(fmaf(b2f(u[1]), c0.y, h0.y), 0.f));
                    w[1] = pack2(fmaxf(fmaf(b2f(u[2]), c0.z, h0.z), 0.f),
                                 fmaxf(fmaf(b2f(u[3]), c0.w, h0.w), 0.f));
                    w[2] = pack2(fmaxf(fmaf(b2f(u[4]), c1.x, h1.x), 0.f),
                                 fmaxf(fmaf(b2f(u[5]), c1.y, h1.y), 0.f));
                    w[3] = pack2(fmaxf(fmaf(b2f(u[6]), c1.z, h1.z), 0.f),
                                 fmaxf(fmaf(b2f(u[7]), c1.w, h1.w), 0.f));
                    short8_t rr;
                    *(uint4*)&rr = *(const uint4*)w;
                    if (z) a1 = rr; else a0 = rr;
                }
            }
            #pragma unroll
            for (int nt = 0; nt < NT; ++nt) {
                short8_t bf = *(const short8_t*)&Bs[(wn * WN + nt * 16 + l16) * 128 + ((j ^ l16) * 8)];
                acc[0][nt] = __builtin_amdgcn_mfma_f32_16x16x32_bf16(a0, bf, acc[0][nt], 0, 0, 0);
                acc[1][nt] = __builtin_amdgcn_mfma_f32_16x16x32_bf16(a1, bf, acc[1][nt], 0, 0, 0);
            }
        }

        #pragma unroll
        for (int mt = 0; mt < 2; ++mt)
            #pragma unroll
            for (int nt = 0; nt < NT; ++nt)
                #pragma unroll
                for (int r = 0; r < 4; ++r) {
                    float v = acc[mt][nt][r] + bvs[nt];
                    acc[mt][nt][r] = v;
                    if (STATS) { sSum[nt] += v; sSq[nt] = fmaf(v, v, sSq[nt]); }
                }
        if (STATS && it == RPT - 1) {
            #pragma unroll
            for (int nt = 0; nt < NT; ++nt) {
                float s = sSum[nt], q = sSq[nt];
                s += __shfl_xor(s, 16); q += __shfl_xor(q, 16);
                s += __shfl_xor(s, 32); q += __shfl_xor(q, 32);
                if (lane < 16) {
                    int col = wn * WN + nt * 16 + l16;
                    sred[(wave * N + col) * 2 + 0] = s;
                    sred[(wave * N + col) * 2 + 1] = q;
                }
            }
        }
        __syncthreads();

        char* eb = (char*)Abuf[it & 1];
        #pragma unroll
        for (int mt = 0; mt < 2; ++mt)
            #pragma unroll
            for (int nt = 0; nt < NT; ++nt) {
                int col = wn * WN + nt * 16 + l16;
                int bc = col * (int)sizeof(CT);
                #pragma unroll
                for (int r = 0; r < 4; ++r) {
                    int row = wm * 32 + mt * 16 + quad * 4 + r;
                    int addr = row * 256 + ((((bc >> 4) ^ (row & 15)) << 4) | (bc & 15));
                    if constexpr (sizeof(CT) == 4) *(float*)(eb + addr) = acc[mt][nt][r];
                    else                           *(ushort_t*)(eb + addr) = f2b(acc[mt][nt][r]);
                }
            }
        if (STATS && it == RPT - 1) {
            int col = tid & (N - 1), qs = tid / N;
            int wb = (col / WN) * 2;
            float v = sred[(wb * N + col) * 2 + qs] + sred[((wb + 1) * N + col) * 2 + qs];
            (qs ? sqP : sumP)[(size_t)blockIdx.x * N + col] = v;
        }
        __syncthreads();

        int r0 = blockIdx.x * (RPT * 64) + it * 64;
        #pragma unroll
        for (int p = 0; p < 4; ++p) {
            int s = p * 256 + tid;
            int row = s >> 4, g = s & 15;
            uint4 v = *(const uint4*)(eb + row * 256 + ((g ^ (row & 15)) << 4));
            *(uint4*)((char*)(C + (size_t)(r0 + row) * N) + g * 16) = v;
        }
    }
}

// ---------------------------------------------------------------------------
// fp32 vector GEMM (layer 0: K=32, fp32 input) with fused stats partials.
// ---------------------------------------------------------------------------
template<int K, int N>
__launch_bounds__(256)
__global__ void gemm_f32_k(const float* __restrict__ A, const float* __restrict__ W,
                           const float* __restrict__ bias, ushort_t* __restrict__ C,
                           float* __restrict__ sumP, float* __restrict__ sqP) {
    constexpr int TX = N / 4;        // 32
    constexpr int TY = 256 / TX;     // 8
    constexpr int RM = TILE_M / TY;  // 8

    __shared__ float As[TILE_M][BK + 1];
    __shared__ float Ws[BK][N];
    __shared__ float redst[2][TY][N];

    const int tid = threadIdx.x;
    const int tx = tid % TX;
    const int ty = tid / TX;
    const int row0 = blockIdx.x * TILE_M;
    const int arow = tid >> 2;
    const int acol = (tid & 3) * 8;

    float acc[RM][4];
    #pragma unroll
    for (int r = 0; r < RM; ++r)
        #pragma unroll
        for (int c = 0; c < 4; ++c) acc[r][c] = 0.f;

    for (int k0 = 0; k0 < K; k0 += BK) {
        {
            const float4* p = (const float4*)&A[(size_t)(row0 + arow) * K + k0 + acol];
            float4 x0 = p[0], x1 = p[1];
            As[arow][acol + 0] = x0.x; As[arow][acol + 1] = x0.y;
            As[arow][acol + 2] = x0.z; As[arow][acol + 3] = x0.w;
            As[arow][acol + 4] = x1.x; As[arow][acol + 5] = x1.y;
            As[arow][acol + 6] = x1.z; As[arow][acol + 7] = x1.w;
        }
        #pragma unroll
        for (int i = 0; i < (BK * N) / 256; ++i) {
            int e = i * 256 + tid;
            Ws[e / N][e % N] = W[(size_t)(k0 + e / N) * N + e % N];
        }
        __syncthreads();
        #pragma unroll
        for (int kk = 0; kk < BK; ++kk) {
            float4 wv = *(const float4*)&Ws[kk][tx * 4];
            #pragma unroll
            for (int r = 0; r < RM; ++r) {
                float a = As[ty * RM + r][kk];
                acc[r][0] = fmaf(a, wv.x, acc[r][0]);
                acc[r][1] = fmaf(a, wv.y, acc[r][1]);
                acc[r][2] = fmaf(a, wv.z, acc[r][2]);
                acc[r][3] = fmaf(a, wv.w, acc[r][3]);
            }
        }
        __syncthreads();
    }
    float4 bv = *(const float4*)&bias[tx * 4];
    float s[4] = {0, 0, 0, 0}, q[4] = {0, 0, 0, 0};
    #pragma unroll
    for (int r = 0; r < RM; ++r) {
        float o[4];
        o[0] = acc[r][0] + bv.x; o[1] = acc[r][1] + bv.y;
        o[2] = acc[r][2] + bv.z; o[3] = acc[r][3] + bv.w;
        #pragma unroll
        for (int c = 0; c < 4; ++c) { s[c] += o[c]; q[c] = fmaf(o[c], o[c], q[c]); }
        size_t off = (size_t)(row0 + ty * RM + r) * N + tx * 4;
        uint2 ov;
        ov.x = pack2(o[0], o[1]);
        ov.y = pack2(o[2], o[3]);
        *(uint2*)&C[off] = ov;
    }
    #pragma unroll
    for (int c = 0; c < 4; ++c) {
        redst[0][ty][tx * 4 + c] = s[c];
        redst[1][ty][tx * 4 + c] = q[c];
    }
    __syncthreads();
    {
        int col = tid & (N - 1), qs = tid / N;
        float v = 0.f;
        #pragma unroll
        for (int t = 0; t < TY; ++t) v += redst[qs][t][col];
        (qs ? sqP : sumP)[(size_t)blockIdx.x * N + col] = v;
    }
}

// ---------------------------------------------------------------------------
// Tree-reduce block partials: P[NBLK][128] -> R2[col*64 + chunk] (64 chunks).
// ---------------------------------------------------------------------------
template<int NBLK>
__global__ __launch_bounds__(256) void reduce1_k(const float* __restrict__ sumP,
                                                 const float* __restrict__ sqP,
                                                 float* __restrict__ sumR2,
                                                 float* __restrict__ sqR2) {
    constexpr int ROWS = NBLK / 64;
    const int tid = threadIdx.x;
    const int qs = blockIdx.x & 1;
    const int chunk = blockIdx.x >> 1;
    const float* src = qs ? sqP : sumP;
    float* dst = qs ? sqR2 : sumR2;
    const int col = tid & 127;
    const int half = tid >> 7;
    float s = 0.f;
    for (int r = half; r < ROWS; r += 2)
        s += src[(size_t)(chunk * ROWS + r) * 128 + col];
    __shared__ float red[256];
    red[tid] = s;
    __syncthreads();
    if (tid < 128) dst[col * 64 + chunk] = red[tid] + red[tid + 128];
}

// Reduce 64 chunks; scale = g*rsqrt(var+eps); shift = be - mean*scale
__global__ void finalize_k(const float* __restrict__ sumR2, const float* __restrict__ sqR2,
                           const float* __restrict__ g, const float* __restrict__ be,
                           float* __restrict__ scale, float* __restrict__ shift) {
    const int f = threadIdx.x;  // 128
    const float4* ps = (const float4*)&sumR2[f * REP];
    const float4* pq = (const float4*)&sqR2[f * REP];
    float s = 0.f, q = 0.f;
    #pragma unroll
    for (int i = 0; i < REP / 4; ++i) {
        float4 a = ps[i]; s += (a.x + a.y) + (a.z + a.w);
        float4 b = pq[i]; q += (b.x + b.y) + (b.z + b.w);
    }
    const float invM = 1.f / (float)M_ROWS;
    float mean = s * invM;
    float var = q * invM - mean * mean;
    float sc = g[f] * rsqrtf(var + 1e-5f);
    scale[f] = sc;
    shift[f] = fmaf(-mean, sc, be[f]);
}

// All four weight transposes in one launch: fp32 W[K][N] -> bf16 WT[N][K]
__global__ void transpose_all_k(const float* __restrict__ W1, const float* __restrict__ W2,
                                const float* __restrict__ W3, const float* __restrict__ W4,
                                ushort_t* __restrict__ wt1, ushort_t* __restrict__ wt2,
                                ushort_t* __restrict__ wt3, ushort_t* __restrict__ wt4) {
    int idx = blockIdx.x * 256 + threadIdx.x;
    if (idx < 32768) {                       // W1: 256 x 128
        int k = idx >> 7, n = idx & 127;
        wt1[(size_t)n * 256 + k] = f2b(W1[idx]);
    } else if (idx < 49152) {                // W2: 128 x 128
        int i = idx - 32768;
        int k = i >> 7, n = i & 127;
        wt2[(size_t)n * 128 + k] = f2b(W2[i]);
    } else if (idx < 65536) {                // W3: 128 x 128
        int i = idx - 49152;
        int k = i >> 7, n = i & 127;
        wt3[(size_t)n * 128 + k] = f2b(W3[i]);
    } else if (idx < 73728) {                // W4: 128 x 64
        int i = idx - 65536;
        int k = i >> 6, n = i & 63;
        wt4[(size_t)n * 128 + k] = f2b(W4[i]);
    }
}

// ---------------------------------------------------------------------------
// Chunked causal cummax, one block per (ba) sequence (T=256, 128 feats).
// INPLACE=0: materialize X = bnrelu(Y) in place AND write P = cummax(X) to P.
// INPLACE=1: write cummax(bnrelu(Y)) in place (pooled-only).
// ---------------------------------------------------------------------------
template<int INPLACE>
__global__ __launch_bounds__(512) void scan_k(ushort_t* __restrict__ Y,
                                              const float* __restrict__ scale,
                                              const float* __restrict__ shift,
                                              ushort_t* __restrict__ P) {
    const int tid = threadIdx.x;
    const int fp = tid & 63;
    const int chunk = tid >> 6;
    const size_t base = (size_t)blockIdx.x * 256 * 128 + fp * 2;
    const float sc0 = scale[fp * 2], sh0 = shift[fp * 2];
    const float sc1 = scale[fp * 2 + 1], sh1 = shift[fp * 2 + 1];

    __shared__ float cmax[8][128];

    uint_t vals[32];
    float run0 = 0.f, run1 = 0.f;
    #pragma unroll
    for (int i = 0; i < 32; ++i) {
        size_t idx = base + (size_t)(chunk * 32 + i) * 128;
        uint_t u = *(const uint_t*)&Y[idx];
        float v0 = fmaxf(fmaf(b2f((ushort_t)(u & 0xffff)), sc0, sh0), 0.f);
        float v1 = fmaxf(fmaf(b2f((ushort_t)(u >> 16)), sc1, sh1), 0.f);
        run0 = fmaxf(run0, v0);
        run1 = fmaxf(run1, v1);
        vals[i] = pack2(v0, v1);
        if (!INPLACE) *(uint_t*)&Y[idx] = vals[i];   // materialize X in place
    }
    cmax[chunk][fp * 2] = run0;
    cmax[chunk][fp * 2 + 1] = run1;
    __syncthreads();
    float p0 = 0.f, p1 = 0.f;
    for (int c = 0; c < chunk; ++c) {
        p0 = fmaxf(p0, cmax[c][fp * 2]);
        p1 = fmaxf(p1, cmax[c][fp * 2 + 1]);
    }
    run0 = p0; run1 = p1;
    ushort_t* dst = INPLACE ? Y : P;
    #pragma unroll
    for (int i = 0; i < 32; ++i) {
        uint_t u = vals[i];
        run0 = fmaxf(run0, b2f((ushort_t)(u & 0xffff)));
        run1 = fmaxf(run1, b2f((ushort_t)(u >> 16)));
        *(uint_t*)&dst[base + (size_t)(chunk * 32 + i) * 128] = pack2(run0, run1);
    }
}

extern "C" void kernel_launch(void* const* d_in, const int* in_sizes, int n_in,
                              void* d_out, int out_size, void* d_ws, size_t ws_size,
                              hipStream_t stream) {
    const float* poly = (const float*)d_in[0];
    const float* W0 = (const float*)d_in[1];
    const float* b0 = (const float*)d_in[2];
    const float* g0 = (const float*)d_in[3];
    const float* be0 = (const float*)d_in[4];
    const float* W1 = (const float*)d_in[5];
    const float* b1 = (const float*)d_in[6];
    const float* g1 = (const float*)d_in[7];
    const float* be1 = (const float*)d_in[8];
    const float* W2 = (const float*)d_in[9];
    const float* b2 = (const float*)d_in[10];
    const float* g2 = (const float*)d_in[11];
    const float* be2 = (const float*)d_in[12];
    const float* W3 = (const float*)d_in[13];
    const float* b3 = (const float*)d_in[14];
    const float* g3 = (const float*)d_in[15];
    const float* be3 = (const float*)d_in[16];
    const float* W4 = (const float*)d_in[17];
    const float* b4 = (const float*)d_in[18];
    float* out = (float*)d_out;

    float* st = (float*)d_ws;
    float* sumP = st;
    float* sqP = st + 524288;
    float* sumR2 = st + 1048576;
    float* sqR2 = sumR2 + 8192;
    float* scsh = st + 1064960;
    auto scP = [&](int i) { return scsh + i * 256; };
    auto shP = [&](int i) { return scsh + i * 256 + 128; };
    ushort_t* wt1 = (ushort_t*)((char*)d_ws + 4263936);         // 128 x 256
    ushort_t* wt2 = wt1 + 128 * 256;                            // 128 x 128
    ushort_t* wt3 = wt2 + 128 * 128;                            // 128 x 128
    ushort_t* wt4 = wt3 + 128 * 128;                            // 64 x 128
    ushort_t* h0 = (ushort_t*)((char*)d_ws + 4263936 + 147456);
    ushort_t* h1 = h0 + (size_t)M_ROWS * 128;
    ushort_t* y1 = (ushort_t*)out;   // d_out doubles as y1 scratch (M*128 bf16
                                     // == out_size bytes); overwritten by L4.

    const int G64 = M_ROWS / TILE_M;    // 4096 (L0)
    const int GP = M_ROWS / (64 * 8);   // 512 (persistent kernels, RPT=8)
    const int GBA = 1024;               // one block per (b,a) sequence

    transpose_all_k<<<288, 256, 0, stream>>>(W1, W2, W3, W4, wt1, wt2, wt3, wt4);

    // Layer 0 (fp32 precision): y0 = poly @ W0 + b0 -> h0 (raw bf16) + partials
    gemm_f32_k<32, 128><<<G64, 256, 0, stream>>>(poly, W0, b0, h0, sumP, sqP);
    reduce1_k<4096><<<128, 256, 0, stream>>>(sumP, sqP, sumR2, sqR2);
    finalize_k<<<1, 128, 0, stream>>>(sumR2, sqR2, g0, be0, scP(0), shP(0));

    // X = bnrelu0(y0) in place in h0; P = cummax(X) -> h1
    scan_k<0><<<GBA, 512, 0, stream>>>(h0, scP(0), shP(0), h1);

    // Layer 1: y1 = [X, P] @ W1 + b1 -> d_out scratch (N-split, L3-ordered halves)
    gemm1s_k<8><<<2 * GP, 256, 0, stream>>>(h0, h1, wt1, b1, y1, sumP, sqP);
    reduce1_k<512><<<128, 256, 0, stream>>>(sumP, sqP, sumR2, sqR2);
    finalize_k<<<1, 128, 0, stream>>>(sumR2, sqR2, g1, be1, scP(1), shP(1));

    // Layer 2: y2 = bnrelu1(y1) @ W2 + b2 : d_out -> h0
    mfma_gemm3_k<128, 1, 1, 8, ushort_t><<<GP, 256, 0, stream>>>(
        y1, wt2, b2, scP(1), shP(1), h0, sumP, sqP);
    reduce1_k<512><<<128, 256, 0, stream>>>(sumP, sqP, sumR2, sqR2);
    finalize_k<<<1, 128, 0, stream>>>(sumR2, sqR2, g2, be2, scP(2), shP(2));

    // pooled = cummax(bnrelu2(y2)) in place in h0
    scan_k<1><<<GBA, 512, 0, stream>>>(h0, scP(2), shP(2), nullptr);

    // Layer 3: y3 = pooled @ W3 + b3 -> h0 (in place), persistent pipeline
    mfma_gemm3_k<128, 0, 1, 8, ushort_t><<<GP, 256, 0, stream>>>(
        h0, wt3, b3, nullptr, nullptr, h0, sumP, sqP);
    reduce1_k<512><<<128, 256, 0, stream>>>(sumP, sqP, sumR2, sqR2);
    finalize_k<<<1, 128, 0, stream>>>(sumR2, sqR2, g3, be3, scP(3), shP(3));

    // Layer 4: out = bnrelu3(y3) @ W4 + b4 -> d_out (fp32; overwrites y1 scratch)
    mfma_gemm3_k<64, 1, 0, 8, float><<<GP, 256, 0, stream>>>(
        h0, wt4, b4, scP(3), shP(3), out, nullptr, nullptr);
}